// Round 15
// baseline (50.265 us; speedup 1.0000x reference)
//
#include <hip/hip_runtime.h>
#include <hip/hip_bf16.h>
#include <math.h>

#define HW   (224 * 224)
#define TXW 32
#define TYH 7
#define HX 34
#define HY 9
#define NPXH (HX * HY)          // 306 halo pixels
#define NUNIT (NPXH * 8)        // 2448 16B-units to stage
#define BPI ((224 / TYH) * (224 / TXW))   // 32*7 = 224 blocks per image

typedef __attribute__((ext_vector_type(8))) short bf16x8;
typedef __attribute__((ext_vector_type(4))) float f32x4;

__device__ __forceinline__ unsigned bf16rne(float f) {
  unsigned u = __float_as_uint(f);
  u += 0x7fffu + ((u >> 16) & 1u);
  return u >> 16;
}
// Compiler-visible f32->bf16 (RNE) pair pack; no inline asm so the
// scheduler can move staging loads/stores across it (m240 lesson).
__device__ __forceinline__ unsigned pack_bf16(float lo, float hi) {
  const unsigned short l = __bfloat16_as_ushort(__float2bfloat16(lo));
  const unsigned short h = __bfloat16_as_ushort(__float2bfloat16(hi));
  return (unsigned)l | ((unsigned)h << 16);
}
#define LOG2E 1.4426950408889634f

// ---------------------------------------------------------------------------
// kpack: blocks 0..4: single-pass bf16 B fragments, wb[kk*64+lane] (uint4),
// 1152 items. Block 5: wwv[j] = sum_d w3[d][j]^2.
// ---------------------------------------------------------------------------
__global__ __launch_bounds__(256) void kpack(
    const float* __restrict__ w1, const float* __restrict__ w2,
    const float* __restrict__ w3, const float* __restrict__ w4,
    const float* __restrict__ w5, unsigned short* __restrict__ wb,
    float* __restrict__ wwv)
{
  const int tid = threadIdx.x;
  const int bid = blockIdx.x;
  if (bid == 5) {
    if (tid < 64) {
      const int lane = tid;
      float pw0=0.f, pw1=0.f, pw2=0.f, pw3=0.f;
      for (int it = 0; it < 9; ++it) {
        const int d = lane + it*64;
        const float v0=w3[d*4+0], v1=w3[d*4+1], v2=w3[d*4+2], v3=w3[d*4+3];
        pw0=fmaf(v0,v0,pw0); pw1=fmaf(v1,v1,pw1);
        pw2=fmaf(v2,v2,pw2); pw3=fmaf(v3,v3,pw3);
      }
      for (int off = 32; off > 0; off >>= 1) {
        pw0 += __shfl_down(pw0,off); pw1 += __shfl_down(pw1,off);
        pw2 += __shfl_down(pw2,off); pw3 += __shfl_down(pw3,off);
      }
      if (lane == 0) { wwv[0]=pw0; wwv[1]=pw1; wwv[2]=pw2; wwv[3]=pw3; }
    }
    return;
  }
  const int item = bid*256 + tid;        // 0..1151
  if (item >= 1152) return;
  const int kk   = item >> 6;
  const int l    = item & 63;
  const int col  = l & 15, kg = l >> 4;
  unsigned short hs[8];
#pragma unroll
  for (int i = 0; i < 8; ++i) {
    const int k = kk*32 + kg*8 + i;
    const int s = k >> 6, c = k & 63;
    const int d = c*9 + s;
    float v = (col==0) ? w1[d] : (col==1) ? w2[d] :
              (col<6)  ? w3[d*4 + (col-2)] :
              (col<11) ? w4[d*5 + (col-6)] : w5[d*5 + (col-11)];
    hs[i] = (unsigned short)bf16rne(v);
  }
  uint4 pk;
  pk.x = hs[0] | ((unsigned)hs[1] << 16);
  pk.y = hs[2] | ((unsigned)hs[3] << 16);
  pk.z = hs[4] | ((unsigned)hs[5] << 16);
  pk.w = hs[6] | ((unsigned)hs[7] << 16);
  ((uint4*)wb)[kk*64 + l] = pk;
}

// ---------------------------------------------------------------------------
// kmain: 448 thr (7 waves), tile 32x7, halo 34x9 bf16 in LDS, XOR swizzle,
// 4 blocks/CU (LDS 40392 B). R15 vs R13 (champion):
//  (a) staging conversion via __float2bfloat16 (no inline asm -> scheduler
//      can hoist/overlap staging loads; m240);
//  (b) 2-deep A-fragment prefetch with explicitly named regs (covers the
//      ~120cyc ds_read_b128 latency the 1-deep pipe half-exposed).
// xx via s2l + per-wave box-sum (R14 proved Gram-MFMA xx is a regression).
// ---------------------------------------------------------------------------
__global__ __launch_bounds__(448, 7) void kmain(
    const float* __restrict__ x, const unsigned short* __restrict__ wb,
    const float* __restrict__ wwv, const float* __restrict__ gpt,
    const float* __restrict__ c4p, const float* __restrict__ c5p,
    float* __restrict__ out)
{
  __shared__ __align__(16) uint4 xl16[NPXH * 8];   // 39168 B
  __shared__ float s2l[NPXH];                      // 1224 B -> total 40392

  const int tid = threadIdx.x;
  const int bid = blockIdx.x;
  const int b   = bid / BPI;
  const int t   = bid - b*BPI;
  const int tyi = t / 7;                 // 0..31
  const int txi = t - tyi*7;             // 0..6
  const int y0  = tyi * TYH;
  const int x0  = txi * TXW;
  const float* __restrict__ xb = x + (size_t)b * HW * 64;

  const int lane   = tid & 63;
  const int wv     = tid >> 6;       // 0..6
  const int colsel = lane & 15;
  const int kg     = lane >> 4;

  // ---- B-ring preload at entry: latency hidden under staging ----
  const bf16x8* __restrict__ wbv = (const bf16x8*)wb;
  bf16x8 bq0 = wbv[0*64 + lane];
  bf16x8 bq1 = wbv[1*64 + lane];
  bf16x8 bq2 = wbv[2*64 + lane];

  // ---- Stage halo: 6 rounds (5 full + tail) in two 3-round batches ----
  const int u = tid & 7;
  {
    const int px0 = tid >> 3;        // 0..55
    int hy = (px0 >= HX) ? 1 : 0;
    int hx = px0 - hy*HX;
    int hys[6], hxs[6];
#pragma unroll
    for (int i = 0; i < 6; ++i) {
      hys[i] = hy; hxs[i] = hx;
      hy += 1; hx += 22;               // px += 56 == += HX + 22
      if (hx >= HX) { hx -= HX; hy += 1; }
    }
    auto do_batch = [&](int base) {
      float4 va[3], vb[3];
#pragma unroll
      for (int i = 0; i < 3; ++i) {
        const int ri = base + i;
        va[i] = make_float4(0.f,0.f,0.f,0.f);
        vb[i] = make_float4(0.f,0.f,0.f,0.f);
        const bool live = (ri < 5) || (tid < 208);
        if (live) {
          const int gy = y0 + hys[ri] - 1;
          const int gx = x0 + hxs[ri] - 1;
          if ((unsigned)gy < 224u && (unsigned)gx < 224u) {
            const float* src = xb + ((size_t)gy*224 + gx)*64 + u*8;
            va[i] = *(const float4*)src;
            vb[i] = *(const float4*)(src + 4);
          }
        }
      }
#pragma unroll
      for (int i = 0; i < 3; ++i) {
        const int ri = base + i;
        const bool live = (ri < 5) || (tid < 208);
        if (live) {
          const int pxv = hys[ri]*HX + hxs[ri];
          float p2 = fmaf(va[i].x,va[i].x, fmaf(va[i].y,va[i].y,
                     fmaf(va[i].z,va[i].z, va[i].w*va[i].w)));
          p2 = fmaf(vb[i].x,vb[i].x, fmaf(vb[i].y,vb[i].y,
               fmaf(vb[i].z,vb[i].z, fmaf(vb[i].w,vb[i].w, p2))));
          p2 += __shfl_xor(p2, 1);
          p2 += __shfl_xor(p2, 2);
          p2 += __shfl_xor(p2, 4);
          uint4 pk;
          pk.x = pack_bf16(va[i].x, va[i].y);
          pk.y = pack_bf16(va[i].z, va[i].w);
          pk.z = pack_bf16(vb[i].x, vb[i].y);
          pk.w = pack_bf16(vb[i].z, vb[i].w);
          xl16[pxv*8 + (u ^ (pxv & 7))] = pk;
          if (u == 0) s2l[pxv] = p2;
        }
      }
    };
    do_batch(0);
    do_batch(3);
  }
  __syncthreads();

  // ---- Per-wave xx box-sum (wave wv owns output row wv) ----
  const int bcol = lane & 31;
  float xxv = 0.f;
#pragma unroll
  for (int dy = 0; dy < 3; ++dy)
#pragma unroll
    for (int dx = 0; dx < 3; ++dx)
      xxv += s2l[(wv + dy)*HX + bcol + dx];

  // ---- MFMA K-loop: row wv, two 16-px halves; 3-deep B ring,
  //      2-deep A prefetch (named regs, fully unrolled) ----
  f32x4 acc0 = (f32x4){0.f,0.f,0.f,0.f};
  f32x4 acc1 = (f32x4){0.f,0.f,0.f,0.f};
  const int pxr = wv*HX + colsel;

  auto aptr = [&](int kk, int half) -> const bf16x8* {
    const int s9 = kk >> 1;
    const int ky = s9 / 3, kx = s9 - ky*3;
    const int uu = (kk & 1)*4 + kg;
    const int px = pxr + ky*HX + kx + half*16;
    return (const bf16x8*)&xl16[px*8 + (uu ^ (px & 7))];
  };

  __builtin_amdgcn_s_setprio(1);
  // 2-deep pipeline: p (current), q (next); load kk+2 into the retiring slot.
  bf16x8 p0 = *aptr(0, 0), p1 = *aptr(0, 1);
  bf16x8 q0 = *aptr(1, 0), q1 = *aptr(1, 1);
#pragma unroll
  for (int kk = 0; kk < 18; ++kk) {
    bf16x8 n0, n1;
    if (kk < 16) { n0 = *aptr(kk+2, 0); n1 = *aptr(kk+2, 1); }
    const int ring = kk % 3;
    const bf16x8 cb = (ring == 0) ? bq0 : (ring == 1) ? bq1 : bq2;
    if (kk < 15) {
      if (ring == 0)      bq0 = wbv[(kk+3)*64 + lane];
      else if (ring == 1) bq1 = wbv[(kk+3)*64 + lane];
      else                bq2 = wbv[(kk+3)*64 + lane];
    }
    acc0 = __builtin_amdgcn_mfma_f32_16x16x32_bf16(p0, cb, acc0, 0, 0, 0);
    acc1 = __builtin_amdgcn_mfma_f32_16x16x32_bf16(p1, cb, acc1, 0, 0, 0);
    p0 = q0; p1 = q1;
    q0 = n0; q1 = n1;
  }
  __builtin_amdgcn_s_setprio(0);

  // ---- Epilogue: D layout col=lane&15, row=kg*4+r ----
  const float g = gpt[0], cc4 = c4p[0], cc5 = c5p[0];
  const float ek = -g * LOG2E;
  const float wwsel = (colsel >= 2 && colsel < 6) ? wwv[colsel - 2] : 0.f;
  const int gy = y0 + wv;

#pragma unroll
  for (int j = 0; j < 2; ++j) {
    const int xh = j*16;
    float rv[4], xr[4];
#pragma unroll
    for (int r = 0; r < 4; ++r) {
      rv[r] = (j == 0) ? acc0[r] : acc1[r];
      xr[r] = __shfl(xxv, xh + kg*4 + r);
    }
    if (colsel == 1) {
#pragma unroll
      for (int r = 0; r < 4; ++r) {
        const float a = fminf(fmaxf(rv[r], -30.f), 30.f);
        const float e2 = __builtin_exp2f(a * (2.f*LOG2E));
        rv[r] = 1.f - 2.f*__builtin_amdgcn_rcpf(e2 + 1.f);
      }
    } else if (colsel >= 2 && colsel < 6) {
#pragma unroll
      for (int r = 0; r < 4; ++r)
        rv[r] = __builtin_exp2f(ek * (xr[r] - 2.f*rv[r] + wwsel));
    } else if (colsel >= 6 && colsel < 11) {
#pragma unroll
      for (int r = 0; r < 4; ++r) { const float uq = rv[r] + cc4; rv[r] = uq*uq*uq; }
    } else if (colsel >= 11) {
#pragma unroll
      for (int r = 0; r < 4; ++r) { const float uq = rv[r] + cc5; const float q = uq*uq; rv[r] = q*q*uq; }
    }
#pragma unroll
    for (int r = 0; r < 4; ++r) {
      const int gx = x0 + xh + kg*4 + r;
      __builtin_nontemporal_store(rv[r], &out[(((size_t)b*224 + gy)*224 + gx)*16 + colsel]);
    }
  }
}

extern "C" void kernel_launch(void* const* d_in, const int* in_sizes, int n_in,
                              void* d_out, int out_size, void* d_ws, size_t ws_size,
                              hipStream_t stream) {
  const float* x  = (const float*)d_in[0];
  const float* w1 = (const float*)d_in[1];
  const float* w2 = (const float*)d_in[2];
  const float* w3 = (const float*)d_in[3];
  const float* w4 = (const float*)d_in[4];
  const float* w5 = (const float*)d_in[5];
  const float* g  = (const float*)d_in[6];
  const float* c4 = (const float*)d_in[7];
  const float* c5 = (const float*)d_in[8];
  float* out = (float*)d_out;

  unsigned short* wb = (unsigned short*)d_ws;   // 1152 uint4 = 18432 B
  float* wwv = (float*)((char*)d_ws + 18432);   // 4 floats

  kpack<<<6, 256, 0, stream>>>(w1, w2, w3, w4, w5, wb, wwv);
  kmain<<<8 * BPI, 448, 0, stream>>>(x, wb, wwv, g, c4, c5, out);
}

// Round 16
// 38.943 us; speedup vs baseline: 1.2907x; 1.2907x over previous
//
#include <hip/hip_runtime.h>
#include <math.h>

#define HW   (224 * 224)
#define TXW 32
#define TYH 7
#define HX 34
#define HY 9
#define NPXH (HX * HY)          // 306 halo pixels
#define NUNIT (NPXH * 8)        // 2448 16B-units to stage
#define BPI ((224 / TYH) * (224 / TXW))   // 32*7 = 224 blocks per image

typedef __attribute__((ext_vector_type(8))) short bf16x8;
typedef __attribute__((ext_vector_type(4))) float f32x4;

__device__ __forceinline__ unsigned bf16rne(float f) {
  unsigned u = __float_as_uint(f);
  u += 0x7fffu + ((u >> 16) & 1u);
  return u >> 16;
}
// Single-instruction packed f32->bf16 (RNE). R15 proved the __float2bfloat16
// builtin expansion is SLOWER here (staging critical path) — keep the asm.
__device__ __forceinline__ unsigned cvt_pk_bf16(float lo, float hi) {
  unsigned r;
  asm("v_cvt_pk_bf16_f32 %0, %1, %2" : "=v"(r) : "v"(lo), "v"(hi));
  return r;
}
#define LOG2E 1.4426950408889634f

// ---------------------------------------------------------------------------
// kpack: blocks 0..4: single-pass bf16 B fragments, wb[kk*64+lane] (uint4),
// 1152 items. Block 5: wwv[j] = sum_d w3[d][j]^2.
// ---------------------------------------------------------------------------
__global__ __launch_bounds__(256) void kpack(
    const float* __restrict__ w1, const float* __restrict__ w2,
    const float* __restrict__ w3, const float* __restrict__ w4,
    const float* __restrict__ w5, unsigned short* __restrict__ wb,
    float* __restrict__ wwv)
{
  const int tid = threadIdx.x;
  const int bid = blockIdx.x;
  if (bid == 5) {
    if (tid < 64) {
      const int lane = tid;
      float pw0=0.f, pw1=0.f, pw2=0.f, pw3=0.f;
      for (int it = 0; it < 9; ++it) {
        const int d = lane + it*64;
        const float v0=w3[d*4+0], v1=w3[d*4+1], v2=w3[d*4+2], v3=w3[d*4+3];
        pw0=fmaf(v0,v0,pw0); pw1=fmaf(v1,v1,pw1);
        pw2=fmaf(v2,v2,pw2); pw3=fmaf(v3,v3,pw3);
      }
      for (int off = 32; off > 0; off >>= 1) {
        pw0 += __shfl_down(pw0,off); pw1 += __shfl_down(pw1,off);
        pw2 += __shfl_down(pw2,off); pw3 += __shfl_down(pw3,off);
      }
      if (lane == 0) { wwv[0]=pw0; wwv[1]=pw1; wwv[2]=pw2; wwv[3]=pw3; }
    }
    return;
  }
  const int item = bid*256 + tid;        // 0..1151
  if (item >= 1152) return;
  const int kk   = item >> 6;
  const int l    = item & 63;
  const int col  = l & 15, kg = l >> 4;
  unsigned short hs[8];
#pragma unroll
  for (int i = 0; i < 8; ++i) {
    const int k = kk*32 + kg*8 + i;
    const int s = k >> 6, c = k & 63;
    const int d = c*9 + s;
    float v = (col==0) ? w1[d] : (col==1) ? w2[d] :
              (col<6)  ? w3[d*4 + (col-2)] :
              (col<11) ? w4[d*5 + (col-6)] : w5[d*5 + (col-11)];
    hs[i] = (unsigned short)bf16rne(v);
  }
  uint4 pk;
  pk.x = hs[0] | ((unsigned)hs[1] << 16);
  pk.y = hs[2] | ((unsigned)hs[3] << 16);
  pk.z = hs[4] | ((unsigned)hs[5] << 16);
  pk.w = hs[6] | ((unsigned)hs[7] << 16);
  ((uint4*)wb)[kk*64 + l] = pk;
}

// ---------------------------------------------------------------------------
// kmain (R13 champion, restored verbatim): 448 thr (7 waves), tile 32x7,
// halo 34x9 bf16 in LDS, XOR swizzle, 4 blocks/CU (LDS 40392 B).
// Staging: 6 rounds in two 3-round load-upfront batches; xx via s2l +
// per-wave box-sum (R14: Gram-MFMA xx regresses); K-loop: 3-deep B ring,
// 1-deep A pipe (R15: 2-deep collapses — compiler refuses, VGPR fell to 36);
// cvt_pk inline asm (R15: builtin slower); setprio; nontemporal stores.
// ---------------------------------------------------------------------------
__global__ __launch_bounds__(448, 7) void kmain(
    const float* __restrict__ x, const unsigned short* __restrict__ wb,
    const float* __restrict__ wwv, const float* __restrict__ gpt,
    const float* __restrict__ c4p, const float* __restrict__ c5p,
    float* __restrict__ out)
{
  __shared__ __align__(16) uint4 xl16[NPXH * 8];   // 39168 B
  __shared__ float s2l[NPXH];                      // 1224 B -> total 40392

  const int tid = threadIdx.x;
  const int bid = blockIdx.x;
  const int b   = bid / BPI;
  const int t   = bid - b*BPI;
  const int tyi = t / 7;                 // 0..31
  const int txi = t - tyi*7;             // 0..6
  const int y0  = tyi * TYH;
  const int x0  = txi * TXW;
  const float* __restrict__ xb = x + (size_t)b * HW * 64;

  const int lane   = tid & 63;
  const int wv     = tid >> 6;       // 0..6
  const int colsel = lane & 15;
  const int kg     = lane >> 4;

  // ---- B-ring preload at entry: latency hidden under staging ----
  const bf16x8* __restrict__ wbv = (const bf16x8*)wb;
  bf16x8 bq0 = wbv[0*64 + lane];
  bf16x8 bq1 = wbv[1*64 + lane];
  bf16x8 bq2 = wbv[2*64 + lane];

  // ---- Stage halo: 6 rounds (5 full + tail) in two 3-round batches ----
  const int u = tid & 7;
  {
    const int px0 = tid >> 3;        // 0..55
    int hy = (px0 >= HX) ? 1 : 0;
    int hx = px0 - hy*HX;
    int hys[6], hxs[6];
#pragma unroll
    for (int i = 0; i < 6; ++i) {
      hys[i] = hy; hxs[i] = hx;
      hy += 1; hx += 22;               // px += 56 == += HX + 22
      if (hx >= HX) { hx -= HX; hy += 1; }
    }
    auto do_batch = [&](int base) {
      float4 va[3], vb[3];
#pragma unroll
      for (int i = 0; i < 3; ++i) {
        const int ri = base + i;
        va[i] = make_float4(0.f,0.f,0.f,0.f);
        vb[i] = make_float4(0.f,0.f,0.f,0.f);
        const bool live = (ri < 5) || (tid < 208);
        if (live) {
          const int gy = y0 + hys[ri] - 1;
          const int gx = x0 + hxs[ri] - 1;
          if ((unsigned)gy < 224u && (unsigned)gx < 224u) {
            const float* src = xb + ((size_t)gy*224 + gx)*64 + u*8;
            va[i] = *(const float4*)src;
            vb[i] = *(const float4*)(src + 4);
          }
        }
      }
#pragma unroll
      for (int i = 0; i < 3; ++i) {
        const int ri = base + i;
        const bool live = (ri < 5) || (tid < 208);
        if (live) {
          const int pxv = hys[ri]*HX + hxs[ri];
          float p2 = fmaf(va[i].x,va[i].x, fmaf(va[i].y,va[i].y,
                     fmaf(va[i].z,va[i].z, va[i].w*va[i].w)));
          p2 = fmaf(vb[i].x,vb[i].x, fmaf(vb[i].y,vb[i].y,
               fmaf(vb[i].z,vb[i].z, fmaf(vb[i].w,vb[i].w, p2))));
          p2 += __shfl_xor(p2, 1);
          p2 += __shfl_xor(p2, 2);
          p2 += __shfl_xor(p2, 4);
          uint4 pk;
          pk.x = cvt_pk_bf16(va[i].x, va[i].y);
          pk.y = cvt_pk_bf16(va[i].z, va[i].w);
          pk.z = cvt_pk_bf16(vb[i].x, vb[i].y);
          pk.w = cvt_pk_bf16(vb[i].z, vb[i].w);
          xl16[pxv*8 + (u ^ (pxv & 7))] = pk;
          if (u == 0) s2l[pxv] = p2;
        }
      }
    };
    do_batch(0);
    do_batch(3);
  }
  __syncthreads();

  // ---- Per-wave xx box-sum (wave wv owns output row wv) ----
  const int bcol = lane & 31;
  float xxv = 0.f;
#pragma unroll
  for (int dy = 0; dy < 3; ++dy)
#pragma unroll
    for (int dx = 0; dx < 3; ++dx)
      xxv += s2l[(wv + dy)*HX + bcol + dx];

  // ---- MFMA K-loop: row wv, two 16-px halves; 3-deep B ring,
  //      1-deep A software pipeline ----
  f32x4 acc0 = (f32x4){0.f,0.f,0.f,0.f};
  f32x4 acc1 = (f32x4){0.f,0.f,0.f,0.f};
  const int pxr = wv*HX + colsel;

  auto aptr = [&](int kk, int half) -> const bf16x8* {
    const int s9 = kk >> 1;
    const int ky = s9 / 3, kx = s9 - ky*3;
    const int uu = (kk & 1)*4 + kg;
    const int px = pxr + ky*HX + kx + half*16;
    return (const bf16x8*)&xl16[px*8 + (uu ^ (px & 7))];
  };

  __builtin_amdgcn_s_setprio(1);
  bf16x8 a0 = *aptr(0, 0);
  bf16x8 a1 = *aptr(0, 1);
#pragma unroll
  for (int kk = 0; kk < 18; ++kk) {
    bf16x8 na0, na1;
    if (kk < 17) { na0 = *aptr(kk+1, 0); na1 = *aptr(kk+1, 1); }
    const int ring = kk % 3;
    const bf16x8 cb = (ring == 0) ? bq0 : (ring == 1) ? bq1 : bq2;
    if (kk < 15) {
      if (ring == 0)      bq0 = wbv[(kk+3)*64 + lane];
      else if (ring == 1) bq1 = wbv[(kk+3)*64 + lane];
      else                bq2 = wbv[(kk+3)*64 + lane];
    }
    acc0 = __builtin_amdgcn_mfma_f32_16x16x32_bf16(a0, cb, acc0, 0, 0, 0);
    acc1 = __builtin_amdgcn_mfma_f32_16x16x32_bf16(a1, cb, acc1, 0, 0, 0);
    a0 = na0; a1 = na1;
  }
  __builtin_amdgcn_s_setprio(0);

  // ---- Epilogue: D layout col=lane&15, row=kg*4+r ----
  const float g = gpt[0], cc4 = c4p[0], cc5 = c5p[0];
  const float ek = -g * LOG2E;
  const float wwsel = (colsel >= 2 && colsel < 6) ? wwv[colsel - 2] : 0.f;
  const int gy = y0 + wv;

#pragma unroll
  for (int j = 0; j < 2; ++j) {
    const int xh = j*16;
    float rv[4], xr[4];
#pragma unroll
    for (int r = 0; r < 4; ++r) {
      rv[r] = (j == 0) ? acc0[r] : acc1[r];
      xr[r] = __shfl(xxv, xh + kg*4 + r);
    }
    if (colsel == 1) {
#pragma unroll
      for (int r = 0; r < 4; ++r) {
        const float a = fminf(fmaxf(rv[r], -30.f), 30.f);
        const float e2 = __builtin_exp2f(a * (2.f*LOG2E));
        rv[r] = 1.f - 2.f*__builtin_amdgcn_rcpf(e2 + 1.f);
      }
    } else if (colsel >= 2 && colsel < 6) {
#pragma unroll
      for (int r = 0; r < 4; ++r)
        rv[r] = __builtin_exp2f(ek * (xr[r] - 2.f*rv[r] + wwsel));
    } else if (colsel >= 6 && colsel < 11) {
#pragma unroll
      for (int r = 0; r < 4; ++r) { const float uq = rv[r] + cc4; rv[r] = uq*uq*uq; }
    } else if (colsel >= 11) {
#pragma unroll
      for (int r = 0; r < 4; ++r) { const float uq = rv[r] + cc5; const float q = uq*uq; rv[r] = q*q*uq; }
    }
#pragma unroll
    for (int r = 0; r < 4; ++r) {
      const int gx = x0 + xh + kg*4 + r;
      __builtin_nontemporal_store(rv[r], &out[(((size_t)b*224 + gy)*224 + gx)*16 + colsel]);
    }
  }
}

extern "C" void kernel_launch(void* const* d_in, const int* in_sizes, int n_in,
                              void* d_out, int out_size, void* d_ws, size_t ws_size,
                              hipStream_t stream) {
  const float* x  = (const float*)d_in[0];
  const float* w1 = (const float*)d_in[1];
  const float* w2 = (const float*)d_in[2];
  const float* w3 = (const float*)d_in[3];
  const float* w4 = (const float*)d_in[4];
  const float* w5 = (const float*)d_in[5];
  const float* g  = (const float*)d_in[6];
  const float* c4 = (const float*)d_in[7];
  const float* c5 = (const float*)d_in[8];
  float* out = (float*)d_out;

  unsigned short* wb = (unsigned short*)d_ws;   // 1152 uint4 = 18432 B
  float* wwv = (float*)((char*)d_ws + 18432);   // 4 floats

  kpack<<<6, 256, 0, stream>>>(w1, w2, w3, w4, w5, wb, wwv);
  kmain<<<8 * BPI, 448, 0, stream>>>(x, wb, wwv, g, c4, c5, out);
}

// Round 17
// 34.692 us; speedup vs baseline: 1.4489x; 1.1225x over previous
//
#include <hip/hip_runtime.h>
#include <math.h>

#define HW   (224 * 224)
#define TXW 32
#define TYH 7
#define HX 34
#define HY 9
#define NPXH (HX * HY)          // 306 halo pixels
#define NUNIT (NPXH * 8)        // 2448 16B-units to stage
#define BPI ((224 / TYH) * (224 / TXW))   // 32*7 = 224 blocks per image

typedef __attribute__((ext_vector_type(8))) short bf16x8;
typedef __attribute__((ext_vector_type(4))) float f32x4;

__device__ __forceinline__ unsigned bf16rne(float f) {
  unsigned u = __float_as_uint(f);
  u += 0x7fffu + ((u >> 16) & 1u);
  return u >> 16;
}
// Single-instruction packed f32->bf16 (RNE). R15 proved the __float2bfloat16
// builtin expansion is SLOWER here (staging critical path) — keep the asm.
__device__ __forceinline__ unsigned cvt_pk_bf16(float lo, float hi) {
  unsigned r;
  asm("v_cvt_pk_bf16_f32 %0, %1, %2" : "=v"(r) : "v"(lo), "v"(hi));
  return r;
}
#define LOG2E 1.4426950408889634f

// ---------------------------------------------------------------------------
// kpack: blocks 0..4: single-pass bf16 B fragments, wb[kk*64+lane] (uint4),
// 1152 items. Block 5: wwv[j] = sum_d w3[d][j]^2.
// ---------------------------------------------------------------------------
__global__ __launch_bounds__(256) void kpack(
    const float* __restrict__ w1, const float* __restrict__ w2,
    const float* __restrict__ w3, const float* __restrict__ w4,
    const float* __restrict__ w5, unsigned short* __restrict__ wb,
    float* __restrict__ wwv)
{
  const int tid = threadIdx.x;
  const int bid = blockIdx.x;
  if (bid == 5) {
    if (tid < 64) {
      const int lane = tid;
      float pw0=0.f, pw1=0.f, pw2=0.f, pw3=0.f;
      for (int it = 0; it < 9; ++it) {
        const int d = lane + it*64;
        const float v0=w3[d*4+0], v1=w3[d*4+1], v2=w3[d*4+2], v3=w3[d*4+3];
        pw0=fmaf(v0,v0,pw0); pw1=fmaf(v1,v1,pw1);
        pw2=fmaf(v2,v2,pw2); pw3=fmaf(v3,v3,pw3);
      }
      for (int off = 32; off > 0; off >>= 1) {
        pw0 += __shfl_down(pw0,off); pw1 += __shfl_down(pw1,off);
        pw2 += __shfl_down(pw2,off); pw3 += __shfl_down(pw3,off);
      }
      if (lane == 0) { wwv[0]=pw0; wwv[1]=pw1; wwv[2]=pw2; wwv[3]=pw3; }
    }
    return;
  }
  const int item = bid*256 + tid;        // 0..1151
  if (item >= 1152) return;
  const int kk   = item >> 6;
  const int l    = item & 63;
  const int col  = l & 15, kg = l >> 4;
  unsigned short hs[8];
#pragma unroll
  for (int i = 0; i < 8; ++i) {
    const int k = kk*32 + kg*8 + i;
    const int s = k >> 6, c = k & 63;
    const int d = c*9 + s;
    float v = (col==0) ? w1[d] : (col==1) ? w2[d] :
              (col<6)  ? w3[d*4 + (col-2)] :
              (col<11) ? w4[d*5 + (col-6)] : w5[d*5 + (col-11)];
    hs[i] = (unsigned short)bf16rne(v);
  }
  uint4 pk;
  pk.x = hs[0] | ((unsigned)hs[1] << 16);
  pk.y = hs[2] | ((unsigned)hs[3] << 16);
  pk.z = hs[4] | ((unsigned)hs[5] << 16);
  pk.w = hs[6] | ((unsigned)hs[7] << 16);
  ((uint4*)wb)[kk*64 + l] = pk;
}

// ---------------------------------------------------------------------------
// kmain (R13 champion + T1 XCD swizzle): 448 thr (7 waves), tile 32x7,
// halo 34x9 bf16 in LDS, XOR swizzle, 4 blocks/CU (LDS 40392 B).
// R17 single change: block index remap bid -> (xcd = bid&7, slot = bid>>3),
// image b = xcd, tile t = slot. With round-robin workgroup->XCD dispatch,
// each XCD processes exactly one image; vertical halo neighbors (t +- 7,
// reuse window ~273 KB) stay in that XCD's 4 MB L2 instead of re-fetching
// from L3 across XCDs (default mapping spread them over all 8 L2s).
// Bijective: 1792 blocks = 8 * 224. Perf heuristic only — correctness is
// mapping-independent.
// ---------------------------------------------------------------------------
__global__ __launch_bounds__(448, 7) void kmain(
    const float* __restrict__ x, const unsigned short* __restrict__ wb,
    const float* __restrict__ wwv, const float* __restrict__ gpt,
    const float* __restrict__ c4p, const float* __restrict__ c5p,
    float* __restrict__ out)
{
  __shared__ __align__(16) uint4 xl16[NPXH * 8];   // 39168 B
  __shared__ float s2l[NPXH];                      // 1224 B -> total 40392

  const int tid = threadIdx.x;
  const int bid = blockIdx.x;
  const int b   = bid & 7;               // image = XCD (round-robin dispatch)
  const int t   = bid >> 3;              // tile within image, 0..223
  const int tyi = t / 7;                 // 0..31
  const int txi = t - tyi*7;             // 0..6
  const int y0  = tyi * TYH;
  const int x0  = txi * TXW;
  const float* __restrict__ xb = x + (size_t)b * HW * 64;

  const int lane   = tid & 63;
  const int wv     = tid >> 6;       // 0..6
  const int colsel = lane & 15;
  const int kg     = lane >> 4;

  // ---- B-ring preload at entry: latency hidden under staging ----
  const bf16x8* __restrict__ wbv = (const bf16x8*)wb;
  bf16x8 bq0 = wbv[0*64 + lane];
  bf16x8 bq1 = wbv[1*64 + lane];
  bf16x8 bq2 = wbv[2*64 + lane];

  // ---- Stage halo: 6 rounds (5 full + tail) in two 3-round batches ----
  const int u = tid & 7;
  {
    const int px0 = tid >> 3;        // 0..55
    int hy = (px0 >= HX) ? 1 : 0;
    int hx = px0 - hy*HX;
    int hys[6], hxs[6];
#pragma unroll
    for (int i = 0; i < 6; ++i) {
      hys[i] = hy; hxs[i] = hx;
      hy += 1; hx += 22;               // px += 56 == += HX + 22
      if (hx >= HX) { hx -= HX; hy += 1; }
    }
    auto do_batch = [&](int base) {
      float4 va[3], vb[3];
#pragma unroll
      for (int i = 0; i < 3; ++i) {
        const int ri = base + i;
        va[i] = make_float4(0.f,0.f,0.f,0.f);
        vb[i] = make_float4(0.f,0.f,0.f,0.f);
        const bool live = (ri < 5) || (tid < 208);
        if (live) {
          const int gy = y0 + hys[ri] - 1;
          const int gx = x0 + hxs[ri] - 1;
          if ((unsigned)gy < 224u && (unsigned)gx < 224u) {
            const float* src = xb + ((size_t)gy*224 + gx)*64 + u*8;
            va[i] = *(const float4*)src;
            vb[i] = *(const float4*)(src + 4);
          }
        }
      }
#pragma unroll
      for (int i = 0; i < 3; ++i) {
        const int ri = base + i;
        const bool live = (ri < 5) || (tid < 208);
        if (live) {
          const int pxv = hys[ri]*HX + hxs[ri];
          float p2 = fmaf(va[i].x,va[i].x, fmaf(va[i].y,va[i].y,
                     fmaf(va[i].z,va[i].z, va[i].w*va[i].w)));
          p2 = fmaf(vb[i].x,vb[i].x, fmaf(vb[i].y,vb[i].y,
               fmaf(vb[i].z,vb[i].z, fmaf(vb[i].w,vb[i].w, p2))));
          p2 += __shfl_xor(p2, 1);
          p2 += __shfl_xor(p2, 2);
          p2 += __shfl_xor(p2, 4);
          uint4 pk;
          pk.x = cvt_pk_bf16(va[i].x, va[i].y);
          pk.y = cvt_pk_bf16(va[i].z, va[i].w);
          pk.z = cvt_pk_bf16(vb[i].x, vb[i].y);
          pk.w = cvt_pk_bf16(vb[i].z, vb[i].w);
          xl16[pxv*8 + (u ^ (pxv & 7))] = pk;
          if (u == 0) s2l[pxv] = p2;
        }
      }
    };
    do_batch(0);
    do_batch(3);
  }
  __syncthreads();

  // ---- Per-wave xx box-sum (wave wv owns output row wv) ----
  const int bcol = lane & 31;
  float xxv = 0.f;
#pragma unroll
  for (int dy = 0; dy < 3; ++dy)
#pragma unroll
    for (int dx = 0; dx < 3; ++dx)
      xxv += s2l[(wv + dy)*HX + bcol + dx];

  // ---- MFMA K-loop: row wv, two 16-px halves; 3-deep B ring,
  //      1-deep A software pipeline ----
  f32x4 acc0 = (f32x4){0.f,0.f,0.f,0.f};
  f32x4 acc1 = (f32x4){0.f,0.f,0.f,0.f};
  const int pxr = wv*HX + colsel;

  auto aptr = [&](int kk, int half) -> const bf16x8* {
    const int s9 = kk >> 1;
    const int ky = s9 / 3, kx = s9 - ky*3;
    const int uu = (kk & 1)*4 + kg;
    const int px = pxr + ky*HX + kx + half*16;
    return (const bf16x8*)&xl16[px*8 + (uu ^ (px & 7))];
  };

  __builtin_amdgcn_s_setprio(1);
  bf16x8 a0 = *aptr(0, 0);
  bf16x8 a1 = *aptr(0, 1);
#pragma unroll
  for (int kk = 0; kk < 18; ++kk) {
    bf16x8 na0, na1;
    if (kk < 17) { na0 = *aptr(kk+1, 0); na1 = *aptr(kk+1, 1); }
    const int ring = kk % 3;
    const bf16x8 cb = (ring == 0) ? bq0 : (ring == 1) ? bq1 : bq2;
    if (kk < 15) {
      if (ring == 0)      bq0 = wbv[(kk+3)*64 + lane];
      else if (ring == 1) bq1 = wbv[(kk+3)*64 + lane];
      else                bq2 = wbv[(kk+3)*64 + lane];
    }
    acc0 = __builtin_amdgcn_mfma_f32_16x16x32_bf16(a0, cb, acc0, 0, 0, 0);
    acc1 = __builtin_amdgcn_mfma_f32_16x16x32_bf16(a1, cb, acc1, 0, 0, 0);
    a0 = na0; a1 = na1;
  }
  __builtin_amdgcn_s_setprio(0);

  // ---- Epilogue: D layout col=lane&15, row=kg*4+r ----
  const float g = gpt[0], cc4 = c4p[0], cc5 = c5p[0];
  const float ek = -g * LOG2E;
  const float wwsel = (colsel >= 2 && colsel < 6) ? wwv[colsel - 2] : 0.f;
  const int gy = y0 + wv;

#pragma unroll
  for (int j = 0; j < 2; ++j) {
    const int xh = j*16;
    float rv[4], xr[4];
#pragma unroll
    for (int r = 0; r < 4; ++r) {
      rv[r] = (j == 0) ? acc0[r] : acc1[r];
      xr[r] = __shfl(xxv, xh + kg*4 + r);
    }
    if (colsel == 1) {
#pragma unroll
      for (int r = 0; r < 4; ++r) {
        const float a = fminf(fmaxf(rv[r], -30.f), 30.f);
        const float e2 = __builtin_exp2f(a * (2.f*LOG2E));
        rv[r] = 1.f - 2.f*__builtin_amdgcn_rcpf(e2 + 1.f);
      }
    } else if (colsel >= 2 && colsel < 6) {
#pragma unroll
      for (int r = 0; r < 4; ++r)
        rv[r] = __builtin_exp2f(ek * (xr[r] - 2.f*rv[r] + wwsel));
    } else if (colsel >= 6 && colsel < 11) {
#pragma unroll
      for (int r = 0; r < 4; ++r) { const float uq = rv[r] + cc4; rv[r] = uq*uq*uq; }
    } else if (colsel >= 11) {
#pragma unroll
      for (int r = 0; r < 4; ++r) { const float uq = rv[r] + cc5; const float q = uq*uq; rv[r] = q*q*uq; }
    }
#pragma unroll
    for (int r = 0; r < 4; ++r) {
      const int gx = x0 + xh + kg*4 + r;
      __builtin_nontemporal_store(rv[r], &out[(((size_t)b*224 + gy)*224 + gx)*16 + colsel]);
    }
  }
}

extern "C" void kernel_launch(void* const* d_in, const int* in_sizes, int n_in,
                              void* d_out, int out_size, void* d_ws, size_t ws_size,
                              hipStream_t stream) {
  const float* x  = (const float*)d_in[0];
  const float* w1 = (const float*)d_in[1];
  const float* w2 = (const float*)d_in[2];
  const float* w3 = (const float*)d_in[3];
  const float* w4 = (const float*)d_in[4];
  const float* w5 = (const float*)d_in[5];
  const float* g  = (const float*)d_in[6];
  const float* c4 = (const float*)d_in[7];
  const float* c5 = (const float*)d_in[8];
  float* out = (float*)d_out;

  unsigned short* wb = (unsigned short*)d_ws;   // 1152 uint4 = 18432 B
  float* wwv = (float*)((char*)d_ws + 18432);   // 4 floats

  kpack<<<6, 256, 0, stream>>>(w1, w2, w3, w4, w5, wb, wwv);
  kmain<<<8 * BPI, 448, 0, stream>>>(x, wb, wwv, g, c4, c5, out);
}